// Round 3
// baseline (59.767 us; speedup 1.0000x reference)
//
#include <hip/hip_runtime.h>

// Problem constants
#define BQ   64      // batches
#define CDIM 64      // feature channels
#define DQN  8       // query dim
#define HWN  4096    // H*W
#define KKN  64      // ensemble size

typedef float  f32x4  __attribute__((ext_vector_type(4)));
typedef short  short8 __attribute__((ext_vector_type(8)));

// fp32 -> bf16 round-to-nearest-even
__device__ __forceinline__ ushort f2bf(float x) {
  uint u = __float_as_uint(x);
  u += 0x7fffu + ((u >> 16) & 1u);
  return (ushort)(u >> 16);
}
__device__ __forceinline__ float bf2f(ushort h) {
  return __uint_as_float(((uint)h) << 16);
}

// hi = truncated bf16 (top 16 bits), lo = RNE bf16 of residual.
// |hi-x| <= 2^-7|x|; lo captures residual to 2^-8 rel; dropped al*bl term
// <= 2^-14/product, zero-mean -> dist^2 error ~3e-3 << inter-k gaps O(1-10).
__device__ __forceinline__ void cvtStore(ushort* __restrict__ H,
                                         ushort* __restrict__ L,
                                         int uoff, float4 f) {
  ushort4 h = make_ushort4((ushort)(__float_as_uint(f.x) >> 16),
                           (ushort)(__float_as_uint(f.y) >> 16),
                           (ushort)(__float_as_uint(f.z) >> 16),
                           (ushort)(__float_as_uint(f.w) >> 16));
  ushort4 l = make_ushort4(f2bf(f.x - bf2f(h.x)), f2bf(f.y - bf2f(h.y)),
                           f2bf(f.z - bf2f(h.z)), f2bf(f.w - bf2f(h.w)));
  *(ushort4*)(H + uoff) = h;
  *(ushort4*)(L + uoff) = l;
}

// ---------------------------------------------------------------------------
// K1: partial Gram via split-bf16 MFMA, T14-pipelined.
// A = [F(64 rows); Q(8 rows); zeros(8 rows)]  [80 x hw-chunk]
// S-tile D[i][j] = sum_hw A[rt*16+i][hw] * F[ct*16+j][hw]
// Split x = hi + lo (bf16 each); D ~= Ah*Bh + Ah*Bl + Al*Bh.
// Pipeline per 128-hw chunk: {issue next chunk's global loads to regs} ||
// {ds_read + MFMA on current} -> barrier -> {convert + ds_write next} ->
// barrier.  HBM latency hides under the compute phase (T14).
// 4 waves; wave w owns cols [16w,16w+16); its B fragment == A tile fh[w]
// (uniform switch, static indexing), so 10 ds_read_b128 per K-step, not 12.
// Partial layout: part[blk][row(72)][col(64)], rows 64..71 = G (= Q F^T).
// ---------------------------------------------------------------------------
__global__ __launch_bounds__(256) void k_gram(const float* __restrict__ feat,
                                              const float* __restrict__ qry,
                                              float* __restrict__ part, int chb) {
  __shared__ ushort ldsH[80 * 128];  // hi plane, row stride 128 bf16 = 256B
  __shared__ ushort ldsL[80 * 128];  // lo plane
  int tid = threadIdx.x;
  int wv = tid >> 6, lane = tid & 63;
  int blk = blockIdx.x;
  int b = blk / chb, cb = blk - b * chb;
  int CH = 4096 / chb;
  int hwBase = cb * CH;
  int nch = 32 / chb;  // chunks of 128 hw
  const float* fb = feat + (size_t)b * (CDIM * HWN);
  const float* qb = qry + (size_t)b * (DQN * HWN);

  // zero pad rows 72..79 once (visible after the first stage barrier)
  for (int i = tid; i < 8 * 128; i += 256) {
    ldsH[72 * 128 + i] = 0;
    ldsL[72 * 128 + i] = 0;
  }

  // per-thread staging geometry: 256 threads cover 72 rows x 32 float4s
  int g4 = tid & 31;       // float4 group within 128 hw
  int r8 = tid >> 5;       // row sub-index
  const float* base[9];
  int uoffs[9];
  #pragma unroll
  for (int it = 0; it < 9; ++it) {
    int r = it * 8 + r8;   // 0..71
    base[it] = ((r < 64) ? (fb + (size_t)r * HWN)
                         : (qb + (size_t)(r - 64) * HWN)) + g4 * 4;
    uoffs[it] = r * 128 + ((g4 * 4) ^ ((r & 7) << 3));  // T2 XOR swizzle
  }

  int frow = lane & 15;          // row within 16-row tile
  int fk = (lane >> 4) * 8;      // bf16 offset within 32-hw K-step (16B)
  f32x4 acc[5] = {};

  // prologue: stage chunk 0
  {
    float4 cur[9];
    #pragma unroll
    for (int it = 0; it < 9; ++it)
      cur[it] = *(const float4*)(base[it] + hwBase);
    #pragma unroll
    for (int it = 0; it < 9; ++it) cvtStore(ldsH, ldsL, uoffs[it], cur[it]);
  }
  __syncthreads();

  for (int ch = 0; ch < nch; ++ch) {
    // issue next chunk's HBM loads early (latency hides under compute)
    float4 nxt[9];
    bool hasNext = (ch + 1 < nch);
    if (hasNext) {
      int hw0 = hwBase + (ch + 1) * 128;
      #pragma unroll
      for (int it = 0; it < 9; ++it)
        nxt[it] = *(const float4*)(base[it] + hw0);
    }
    // compute phase on current LDS contents
    #pragma unroll
    for (int ks = 0; ks < 4; ++ks) {
      short8 fh[5], fl[5];
      #pragma unroll
      for (int t = 0; t < 5; ++t) {
        int row = t * 16 + frow;
        int uo = row * 128 + ((ks * 32 + fk) ^ ((row & 7) << 3));
        fh[t] = *(const short8*)(ldsH + uo);
        fl[t] = *(const short8*)(ldsL + uo);
      }
      // B fragment = A tile of this wave's col strip (uniform switch keeps
      // register-array indexing static, rule #20)
      short8 bh, bl;
      switch (wv) {
        case 0:  bh = fh[0]; bl = fl[0]; break;
        case 1:  bh = fh[1]; bl = fl[1]; break;
        case 2:  bh = fh[2]; bl = fl[2]; break;
        default: bh = fh[3]; bl = fl[3]; break;
      }
      #pragma unroll
      for (int t = 0; t < 5; ++t) {
        acc[t] = __builtin_amdgcn_mfma_f32_16x16x32_bf16(fh[t], bh, acc[t], 0, 0, 0);
        acc[t] = __builtin_amdgcn_mfma_f32_16x16x32_bf16(fh[t], bl, acc[t], 0, 0, 0);
        acc[t] = __builtin_amdgcn_mfma_f32_16x16x32_bf16(fl[t], bh, acc[t], 0, 0, 0);
      }
    }
    __syncthreads();
    if (hasNext) {
      #pragma unroll
      for (int it = 0; it < 9; ++it) cvtStore(ldsH, ldsL, uoffs[it], nxt[it]);
      __syncthreads();
    }
  }

  // epilogue: C/D layout col=lane&15, row=(lane>>4)*4+reg
  float* op = part + (size_t)blk * 4608 + wv * 16 + (lane & 15);
  int r0 = (lane >> 4) * 4;
  #pragma unroll
  for (int t = 0; t < 5; ++t) {
    #pragma unroll
    for (int r = 0; r < 4; ++r) {
      int row = t * 16 + r0 + r;
      if (row < 72) op[row * 64] = acc[t][r];
    }
  }
}

// ---------------------------------------------------------------------------
// K1b: reduce the chb chunk-partials per batch; scatter to natural layouts
// Sarr[b][64][64], Garr[b][8][64].  Partials are already [72][64] natural.
// One float4 output per thread: grid = 64*1152/256 = 288 blocks, 8
// independent coalesced 16B loads per thread (latency fully pipelined).
// ---------------------------------------------------------------------------
__global__ __launch_bounds__(256) void k_reduce(const float* __restrict__ part,
                                                float* __restrict__ Sarr,
                                                float* __restrict__ Garr, int chb) {
  int g = blockIdx.x * 256 + threadIdx.x;  // float4 index, 64*1152 total
  int b = g / 1152;
  int o = (g - b * 1152) * 4;              // float offset within [72][64]
  f32x4 s = {};
  #pragma unroll 8
  for (int cb = 0; cb < chb; ++cb) {
    f32x4 p = *(const f32x4*)(part + (size_t)(b * chb + cb) * 4608 + o);
    s += p;
  }
  int r = o >> 6, c = o & 63;              // float4 never spans rows (o%4==0)
  if (r < 64)
    *(f32x4*)(Sarr + b * 4096 + r * 64 + c) = s;
  else
    *(f32x4*)(Garr + b * 512 + (r - 64) * 64 + c) = s;
}

// ---------------------------------------------------------------------------
// K2: dist-score[b,k] = sum_q w^T S w - 2 w^T G  (||q||^2 const per b, dropped)
// One wave per (b,k); lane = i; fp64 epilogue accumulation + wave reduce.
// ---------------------------------------------------------------------------
__global__ __launch_bounds__(256) void k_dist(const float* __restrict__ Sarr,
                                              const float* __restrict__ Garr,
                                              const float* __restrict__ wt,
                                              float* __restrict__ dist) {
  __shared__ float wl[4][512];
  int tid = threadIdx.x, wv = tid >> 6, lane = tid & 63;
  int wid = blockIdx.x * 4 + wv;
  int b = wid >> 6, k = wid & 63;
  for (int t = lane; t < 512; t += 64) wl[wv][t] = wt[k * 512 + t];
  __syncthreads();
  const float* Sb = Sarr + b * 4096;
  float v[8] = {};
  #pragma unroll 4
  for (int j = 0; j < 64; ++j) {
    float s = Sb[j * 64 + lane];
    #pragma unroll
    for (int q = 0; q < 8; ++q) v[q] = fmaf(s, wl[wv][q * 64 + j], v[q]);
  }
  double red = 0.0;
  #pragma unroll
  for (int q = 0; q < 8; ++q) {
    float wqi = wl[wv][q * 64 + lane];
    float gqi = Garr[b * 512 + q * 64 + lane];
    red += (double)wqi * ((double)v[q] - 2.0 * (double)gqi);
  }
  #pragma unroll
  for (int off = 32; off; off >>= 1) red += __shfl_xor(red, off);
  if (lane == 0) dist[b * 64 + k] = (float)red;
}

// ---------------------------------------------------------------------------
// K3: per-b argmin over k with lowest-index tie-break (== jnp.argmax(-d)).
// ---------------------------------------------------------------------------
__global__ void k_argmin(const float* __restrict__ dist, int* __restrict__ codes,
                         float* __restrict__ outCodes) {
  int b = blockIdx.x, k = threadIdx.x;
  float d = dist[b * 64 + k];
  int bi = k;
  #pragma unroll
  for (int off = 32; off; off >>= 1) {
    float d2 = __shfl_xor(d, off);
    int i2 = __shfl_xor(bi, off);
    if (d2 < d || (d2 == d && i2 < bi)) { d = d2; bi = i2; }
  }
  if (k == 0) { codes[b] = bi; outCodes[b] = (float)bi; }
}

// ---------------------------------------------------------------------------
// K4: recompute selected key_values, write out, fused commit-loss partial.
// Fully-coalesced float4 path; no LDS staging of features needed.
// ---------------------------------------------------------------------------
__global__ __launch_bounds__(256) void k_select(const float* __restrict__ feat,
                                                const float* __restrict__ qry,
                                                const float* __restrict__ wt,
                                                const int* __restrict__ codes,
                                                float* __restrict__ outSel,
                                                float* __restrict__ lossPart) {
  __shared__ float wl[512];
  __shared__ float lred[4];
  int bid = blockIdx.x, tid = threadIdx.x;
  int b = bid >> 2, chunk = bid & 3;
  int code = codes[b];
  wl[tid] = wt[code * 512 + tid];
  wl[tid + 256] = wt[code * 512 + 256 + tid];
  __syncthreads();
  int hw = chunk * 1024 + tid * 4;
  const float* fb = feat + (size_t)b * (CDIM * HWN);
  float4 acc[8] = {};
  #pragma unroll 4
  for (int c = 0; c < 64; ++c) {
    float4 f = *(const float4*)(fb + c * HWN + hw);
    #pragma unroll
    for (int q = 0; q < 8; ++q) {
      float w = wl[q * 64 + c];
      acc[q].x = fmaf(w, f.x, acc[q].x);
      acc[q].y = fmaf(w, f.y, acc[q].y);
      acc[q].z = fmaf(w, f.z, acc[q].z);
      acc[q].w = fmaf(w, f.w, acc[q].w);
    }
  }
  float lsum = 0.f;
  #pragma unroll
  for (int q = 0; q < 8; ++q) {
    size_t off = (size_t)b * 32768 + q * 4096 + hw;
    float4 qv = *(const float4*)(qry + off);
    *(float4*)(outSel + off) = acc[q];
    float dx = acc[q].x - qv.x, dy = acc[q].y - qv.y;
    float dz = acc[q].z - qv.z, dw = acc[q].w - qv.w;
    lsum += dx * dx + dy * dy + dz * dz + dw * dw;
  }
  #pragma unroll
  for (int off = 32; off; off >>= 1) lsum += __shfl_xor(lsum, off);
  if ((tid & 63) == 0) lred[tid >> 6] = lsum;
  __syncthreads();
  if (tid == 0) lossPart[bid] = lred[0] + lred[1] + lred[2] + lred[3];
}

// ---------------------------------------------------------------------------
// K5: finalize commit loss = sum(partials) / (B*DQ*H*W)
// ---------------------------------------------------------------------------
__global__ void k_loss(const float* __restrict__ lossPart, float* __restrict__ outLoss) {
  __shared__ float lred[4];
  int tid = threadIdx.x;
  float s = lossPart[tid];
  #pragma unroll
  for (int off = 32; off; off >>= 1) s += __shfl_xor(s, off);
  if ((tid & 63) == 0) lred[tid >> 6] = s;
  __syncthreads();
  if (tid == 0) outLoss[0] = (lred[0] + lred[1] + lred[2] + lred[3]) * (1.0f / 2097152.0f);
}

extern "C" void kernel_launch(void* const* d_in, const int* in_sizes, int n_in,
                              void* d_out, int out_size, void* d_ws, size_t ws_size,
                              hipStream_t stream) {
  const float* feat = (const float*)d_in[0];  // [64,64,64,64]
  const float* qry  = (const float*)d_in[1];  // [64,8,64,64]
  const float* wt   = (const float*)d_in[2];  // [64,8,64]
  float* out = (float*)d_out;
  float* sel      = out;            // 2097152 floats
  float* outCodes = out + 2097152;  // 64 floats
  float* outLoss  = out + 2097216;  // 1 float

  // workspace carve-up; shrink chunk count if ws is small
  int chb = 8;
  while (chb > 1 &&
         ((size_t)64 * chb * 4608 + 64 * 4096 + 64 * 512 + 4096 + 64 + 256) * 4 > ws_size)
    chb >>= 1;
  float* wsf = (float*)d_ws;
  float* part = wsf;
  float* Sarr = part + (size_t)64 * chb * 4608;
  float* Garr = Sarr + 64 * 4096;
  float* dist = Garr + 64 * 512;
  int*   codes = (int*)(dist + 4096);
  float* lossPart = (float*)(codes + 64);

  k_gram<<<64 * chb, 256, 0, stream>>>(feat, qry, part, chb);
  k_reduce<<<(64 * 1152) / 256, 256, 0, stream>>>(part, Sarr, Garr, chb);
  k_dist<<<1024, 256, 0, stream>>>(Sarr, Garr, wt, dist);
  k_argmin<<<64, 64, 0, stream>>>(dist, codes, outCodes);
  k_select<<<256, 256, 0, stream>>>(feat, qry, wt, codes, sel, lossPart);
  k_loss<<<1, 256, 0, stream>>>(lossPart, outLoss);
}

// Round 4
// 50.440 us; speedup vs baseline: 1.1849x; 1.1849x over previous
//
#include <hip/hip_runtime.h>

// Problem constants
#define BQ   64      // batches
#define CDIM 64      // feature channels
#define DQN  8       // query dim
#define HWN  4096    // H*W
#define KKN  64      // ensemble size

typedef float  f32x4  __attribute__((ext_vector_type(4)));
typedef short  short8 __attribute__((ext_vector_type(8)));

// fp32 -> bf16 round-to-nearest-even
__device__ __forceinline__ ushort f2bf(float x) {
  uint u = __float_as_uint(x);
  u += 0x7fffu + ((u >> 16) & 1u);
  return (ushort)(u >> 16);
}
__device__ __forceinline__ float bf2f(ushort h) {
  return __uint_as_float(((uint)h) << 16);
}

// hi = truncated bf16 (top 16 bits), lo = RNE bf16 of residual.
// dropped al*bl term <= 2^-14/product, zero-mean -> dist^2 error ~3e-3
// << inter-k gaps O(1-10); sel/loss recomputed exactly in fp32 downstream.
__device__ __forceinline__ void cvtStore(ushort* __restrict__ H,
                                         ushort* __restrict__ L,
                                         int uoff, float4 f) {
  ushort4 h = make_ushort4((ushort)(__float_as_uint(f.x) >> 16),
                           (ushort)(__float_as_uint(f.y) >> 16),
                           (ushort)(__float_as_uint(f.z) >> 16),
                           (ushort)(__float_as_uint(f.w) >> 16));
  ushort4 l = make_ushort4(f2bf(f.x - bf2f(h.x)), f2bf(f.y - bf2f(h.y)),
                           f2bf(f.z - bf2f(h.z)), f2bf(f.w - bf2f(h.w)));
  *(ushort4*)(H + uoff) = h;
  *(ushort4*)(L + uoff) = l;
}

// ---------------------------------------------------------------------------
// K1: partial Gram via split-bf16 MFMA.
// A = [F(64 rows); Q(8 rows); zeros(8 rows)]  [80 x hw-chunk]
// D[i][j] = sum_hw A[rt*16+i][hw] * F[ct*16+j][hw];  x = hi+lo (bf16),
// D ~= Ah*Bh + Ah*Bl + Al*Bh.
// Occupancy-first structure (R4): chb=16 -> grid 1024 = 4 blocks/CU
// (LDS 40KB caps at exactly 4); __launch_bounds__(256,4) keeps VGPR<=128.
// Cross-block TLP overlaps stage/compute phases; no in-block prefetch
// (R3 post-mortem: prefetch regs bought nothing at grid-limited occupancy).
// 4 waves; wave w owns cols [16w,16w+16); B fragment == A tile fh[w].
// Partial layout: part[blk][row(72)][col(64)], rows 64..71 = G (= Q F^T).
// ---------------------------------------------------------------------------
__global__ __launch_bounds__(256, 4) void k_gram(const float* __restrict__ feat,
                                                 const float* __restrict__ qry,
                                                 float* __restrict__ part, int chb) {
  __shared__ ushort ldsH[80 * 128];  // hi plane, row stride 128 bf16 = 256B
  __shared__ ushort ldsL[80 * 128];  // lo plane
  int tid = threadIdx.x;
  int wv = tid >> 6, lane = tid & 63;
  int blk = blockIdx.x;
  int b = blk / chb, cb = blk - b * chb;
  int CH = 4096 / chb;           // 256 at chb=16
  int hwBase = cb * CH;
  int nch = CH >> 7;             // 128-hw chunks (2 at chb=16)
  const float* fb = feat + (size_t)b * (CDIM * HWN);
  const float* qb = qry + (size_t)b * (DQN * HWN);

  // zero pad rows 72..79 once (visible after first stage barrier)
  for (int i = tid; i < 8 * 128; i += 256) {
    ldsH[72 * 128 + i] = 0;
    ldsL[72 * 128 + i] = 0;
  }

  int g4 = tid & 31;             // float4 group within 128 hw
  int r8 = tid >> 5;             // row sub-index
  int frow = lane & 15;          // row within 16-row tile
  int fk = (lane >> 4) * 8;      // bf16 offset within 32-hw K-step (16B)
  f32x4 acc[5] = {};

  for (int ch = 0; ch < nch; ++ch) {
    int hw0 = hwBase + ch * 128;
    // stage 72 rows x 128 hw: fp32 -> bf16 hi/lo, T2 XOR-swizzled writes
    #pragma unroll
    for (int it = 0; it < 9; ++it) {
      int r = it * 8 + r8;       // 0..71
      const float* src = (r < 64) ? (fb + (size_t)r * HWN + hw0 + g4 * 4)
                                  : (qb + (size_t)(r - 64) * HWN + hw0 + g4 * 4);
      float4 f = *(const float4*)src;
      int uoff = r * 128 + ((g4 * 4) ^ ((r & 7) << 3));
      cvtStore(ldsH, ldsL, uoff, f);
    }
    __syncthreads();
    #pragma unroll
    for (int ks = 0; ks < 4; ++ks) {
      // A fragments: 5 row-tiles {0,16,32,48,64(Q+pad)}, hi & lo planes
      short8 fh[5], fl[5];
      #pragma unroll
      for (int t = 0; t < 5; ++t) {
        int row = t * 16 + frow;
        int uo = row * 128 + ((ks * 32 + fk) ^ ((row & 7) << 3));
        fh[t] = *(const short8*)(ldsH + uo);
        fl[t] = *(const short8*)(ldsL + uo);
      }
      // B fragment = A tile of this wave's col strip (uniform switch keeps
      // register-array indexing static, rule #20)
      short8 bh, bl;
      switch (wv) {
        case 0:  bh = fh[0]; bl = fl[0]; break;
        case 1:  bh = fh[1]; bl = fl[1]; break;
        case 2:  bh = fh[2]; bl = fl[2]; break;
        default: bh = fh[3]; bl = fl[3]; break;
      }
      #pragma unroll
      for (int t = 0; t < 5; ++t) {
        acc[t] = __builtin_amdgcn_mfma_f32_16x16x32_bf16(fh[t], bh, acc[t], 0, 0, 0);
        acc[t] = __builtin_amdgcn_mfma_f32_16x16x32_bf16(fh[t], bl, acc[t], 0, 0, 0);
        acc[t] = __builtin_amdgcn_mfma_f32_16x16x32_bf16(fl[t], bh, acc[t], 0, 0, 0);
      }
    }
    __syncthreads();
  }

  // epilogue: C/D layout col=lane&15, row=(lane>>4)*4+reg
  float* op = part + (size_t)blk * 4608 + wv * 16 + (lane & 15);
  int r0 = (lane >> 4) * 4;
  #pragma unroll
  for (int t = 0; t < 5; ++t) {
    #pragma unroll
    for (int r = 0; r < 4; ++r) {
      int row = t * 16 + r0 + r;
      if (row < 72) op[row * 64] = acc[t][r];
    }
  }
}

// ---------------------------------------------------------------------------
// K1b: reduce the chb chunk-partials per batch; scatter to natural layouts
// Sarr[b][64][64], Garr[b][8][64].  One float4 output per thread:
// grid = 64*1152/256 = 288 blocks, chb independent coalesced 16B loads.
// ---------------------------------------------------------------------------
__global__ __launch_bounds__(256) void k_reduce(const float* __restrict__ part,
                                                float* __restrict__ Sarr,
                                                float* __restrict__ Garr, int chb) {
  int g = blockIdx.x * 256 + threadIdx.x;  // float4 index, 64*1152 total
  int b = g / 1152;
  int o = (g - b * 1152) * 4;              // float offset within [72][64]
  f32x4 s = {};
  #pragma unroll 8
  for (int cb = 0; cb < chb; ++cb) {
    f32x4 p = *(const f32x4*)(part + (size_t)(b * chb + cb) * 4608 + o);
    s += p;
  }
  int r = o >> 6, c = o & 63;              // float4 never spans rows
  if (r < 64)
    *(f32x4*)(Sarr + b * 4096 + r * 64 + c) = s;
  else
    *(f32x4*)(Garr + b * 512 + (r - 64) * 64 + c) = s;
}

// ---------------------------------------------------------------------------
// K2: dist-score[b,k] = sum_q w^T S w - 2 w^T G  (||q||^2 const per b, dropped)
// One wave per (b,k); lane = i; fp64 epilogue accumulation + wave reduce.
// ---------------------------------------------------------------------------
__global__ __launch_bounds__(256) void k_dist(const float* __restrict__ Sarr,
                                              const float* __restrict__ Garr,
                                              const float* __restrict__ wt,
                                              float* __restrict__ dist) {
  __shared__ float wl[4][512];
  int tid = threadIdx.x, wv = tid >> 6, lane = tid & 63;
  int wid = blockIdx.x * 4 + wv;
  int b = wid >> 6, k = wid & 63;
  for (int t = lane; t < 512; t += 64) wl[wv][t] = wt[k * 512 + t];
  __syncthreads();
  const float* Sb = Sarr + b * 4096;
  float v[8] = {};
  #pragma unroll 4
  for (int j = 0; j < 64; ++j) {
    float s = Sb[j * 64 + lane];
    #pragma unroll
    for (int q = 0; q < 8; ++q) v[q] = fmaf(s, wl[wv][q * 64 + j], v[q]);
  }
  double red = 0.0;
  #pragma unroll
  for (int q = 0; q < 8; ++q) {
    float wqi = wl[wv][q * 64 + lane];
    float gqi = Garr[b * 512 + q * 64 + lane];
    red += (double)wqi * ((double)v[q] - 2.0 * (double)gqi);
  }
  #pragma unroll
  for (int off = 32; off; off >>= 1) red += __shfl_xor(red, off);
  if (lane == 0) dist[b * 64 + k] = (float)red;
}

// ---------------------------------------------------------------------------
// K4: inline per-block argmin (redundant, trivial) + recompute selected
// key_values, write out, fused commit-loss partial.  chunk-0 block writes
// outCodes.  Per-element arithmetic identical to prior rounds ->
// sel/loss bit-identical.
// ---------------------------------------------------------------------------
__global__ __launch_bounds__(256) void k_select(const float* __restrict__ feat,
                                                const float* __restrict__ qry,
                                                const float* __restrict__ wt,
                                                const float* __restrict__ dist,
                                                float* __restrict__ outSel,
                                                float* __restrict__ outCodes,
                                                float* __restrict__ lossPart) {
  __shared__ float wl[512];
  __shared__ float lred[4];
  int bid = blockIdx.x, tid = threadIdx.x;
  int b = bid >> 2, chunk = bid & 2 ? (bid & 3) : (bid & 3);
  chunk = bid & 3;
  // argmin over 64 dist values with lowest-index tie-break (== argmax(-d))
  int lane = tid & 63;
  float d = dist[b * 64 + lane];
  int bi = lane;
  #pragma unroll
  for (int off = 32; off; off >>= 1) {
    float d2 = __shfl_xor(d, off);
    int i2 = __shfl_xor(bi, off);
    if (d2 < d || (d2 == d && i2 < bi)) { d = d2; bi = i2; }
  }
  int code = bi;  // identical in every lane/wave (same input data)
  if (chunk == 0 && tid == 0) outCodes[b] = (float)code;
  wl[tid] = wt[code * 512 + tid];
  wl[tid + 256] = wt[code * 512 + 256 + tid];
  __syncthreads();
  int hw = chunk * 1024 + tid * 4;
  const float* fb = feat + (size_t)b * (CDIM * HWN);
  float4 acc[8] = {};
  #pragma unroll 4
  for (int c = 0; c < 64; ++c) {
    float4 f = *(const float4*)(fb + c * HWN + hw);
    #pragma unroll
    for (int q = 0; q < 8; ++q) {
      float w = wl[q * 64 + c];
      acc[q].x = fmaf(w, f.x, acc[q].x);
      acc[q].y = fmaf(w, f.y, acc[q].y);
      acc[q].z = fmaf(w, f.z, acc[q].z);
      acc[q].w = fmaf(w, f.w, acc[q].w);
    }
  }
  float lsum = 0.f;
  #pragma unroll
  for (int q = 0; q < 8; ++q) {
    size_t off = (size_t)b * 32768 + q * 4096 + hw;
    float4 qv = *(const float4*)(qry + off);
    *(float4*)(outSel + off) = acc[q];
    float dx = acc[q].x - qv.x, dy = acc[q].y - qv.y;
    float dz = acc[q].z - qv.z, dw = acc[q].w - qv.w;
    lsum += dx * dx + dy * dy + dz * dz + dw * dw;
  }
  #pragma unroll
  for (int off = 32; off; off >>= 1) lsum += __shfl_xor(lsum, off);
  if ((tid & 63) == 0) lred[tid >> 6] = lsum;
  __syncthreads();
  if (tid == 0) lossPart[bid] = lred[0] + lred[1] + lred[2] + lred[3];
}

// ---------------------------------------------------------------------------
// K5: finalize commit loss = sum(partials) / (B*DQ*H*W)
// ---------------------------------------------------------------------------
__global__ void k_loss(const float* __restrict__ lossPart, float* __restrict__ outLoss) {
  __shared__ float lred[4];
  int tid = threadIdx.x;
  float s = lossPart[tid];
  #pragma unroll
  for (int off = 32; off; off >>= 1) s += __shfl_xor(s, off);
  if ((tid & 63) == 0) lred[tid >> 6] = s;
  __syncthreads();
  if (tid == 0) outLoss[0] = (lred[0] + lred[1] + lred[2] + lred[3]) * (1.0f / 2097152.0f);
}

extern "C" void kernel_launch(void* const* d_in, const int* in_sizes, int n_in,
                              void* d_out, int out_size, void* d_ws, size_t ws_size,
                              hipStream_t stream) {
  const float* feat = (const float*)d_in[0];  // [64,64,64,64]
  const float* qry  = (const float*)d_in[1];  // [64,8,64,64]
  const float* wt   = (const float*)d_in[2];  // [64,8,64]
  float* out = (float*)d_out;
  float* sel      = out;            // 2097152 floats
  float* outCodes = out + 2097152;  // 64 floats
  float* outLoss  = out + 2097216;  // 1 float

  // workspace carve-up; shrink chunk count if ws is small
  int chb = 16;
  while (chb > 1 &&
         ((size_t)64 * chb * 4608 + 64 * 4096 + 64 * 512 + 4096 + 256) * 4 > ws_size)
    chb >>= 1;
  float* wsf = (float*)d_ws;
  float* part = wsf;
  float* Sarr = part + (size_t)64 * chb * 4608;
  float* Garr = Sarr + 64 * 4096;
  float* dist = Garr + 64 * 512;
  float* lossPart = dist + 4096;

  k_gram<<<64 * chb, 256, 0, stream>>>(feat, qry, part, chb);
  k_reduce<<<(64 * 1152) / 256, 256, 0, stream>>>(part, Sarr, Garr, chb);
  k_dist<<<1024, 256, 0, stream>>>(Sarr, Garr, wt, dist);
  k_select<<<256, 256, 0, stream>>>(feat, qry, wt, dist, sel, outCodes, lossPart);
  k_loss<<<1, 256, 0, stream>>>(lossPart, outLoss);
}